// Round 1
// baseline (11253.220 us; speedup 1.0000x reference)
//
#include <hip/hip_runtime.h>

#define DD 128  // feature dim

// ---------------- degree histogram ----------------
__global__ __launch_bounds__(256) void deg_kernel(const int* __restrict__ nidx,
                                                  const int* __restrict__ eidx,
                                                  float* __restrict__ deg_v,
                                                  float* __restrict__ deg_e, int nnz) {
  int i = blockIdx.x * blockDim.x + threadIdx.x;
  if (i < nnz) {
    atomicAdd(&deg_v[nidx[i]], 1.0f);
    atomicAdd(&deg_e[eidx[i]], 1.0f);
  }
}

// ---------------- COO scatter-add of full rows ----------------
// dst[didx[g]] += src[sidx[g]]  (row length DD). 32 lanes per incidence,
// float4 per lane, 8 incidences per 256-thread block.
__global__ __launch_bounds__(256) void scatter_rows(const float* __restrict__ src,
                                                    const int* __restrict__ sidx,
                                                    const int* __restrict__ didx,
                                                    float* __restrict__ dst, int nnz) {
  int g = blockIdx.x * 8 + (threadIdx.x >> 5);
  if (g >= nnz) return;
  int lane = threadIdx.x & 31;
  int s = sidx[g];
  int d = didx[g];
  float4 v = *reinterpret_cast<const float4*>(src + (size_t)s * DD + lane * 4);
  float* o = dst + (size_t)d * DD + lane * 4;
  atomicAdd(o + 0, v.x);
  atomicAdd(o + 1, v.y);
  atomicAdd(o + 2, v.z);
  atomicAdd(o + 3, v.w);
}

// ---------------- fused hyperedge MLP ----------------
// h[e] = (agg[e] * inv_e[e]) @ Wn + ein[e] @ We + b
// 128 threads (thread = output column), 8 rows per block, inputs staged in LDS.
__global__ __launch_bounds__(128) void edge_mlp(const float* __restrict__ agg,
                                                const float* __restrict__ ein,
                                                const float* __restrict__ deg_e,
                                                const float* __restrict__ Wn,
                                                const float* __restrict__ We,
                                                const float* __restrict__ bias,
                                                float* __restrict__ h, int E) {
  const int ROWS = 8;
  __shared__ float sA[ROWS][DD];
  __shared__ float sE[ROWS][DD];
  int r0 = blockIdx.x * ROWS;
  int t = threadIdx.x;
#pragma unroll
  for (int r = 0; r < ROWS; ++r) {
    int row = r0 + r;
    if (row < E) {
      float de = deg_e[row];
      float inv = de > 0.f ? 1.f / de : 0.f;
      sA[r][t] = agg[(size_t)row * DD + t] * inv;
      sE[r][t] = ein[(size_t)row * DD + t];
    } else {
      sA[r][t] = 0.f;
      sE[r][t] = 0.f;
    }
  }
  __syncthreads();

  float acc[ROWS];
  float bv = bias[t];
#pragma unroll
  for (int r = 0; r < ROWS; ++r) acc[r] = bv;

  for (int k = 0; k < DD; ++k) {
    float wn = Wn[k * DD + t];
    float we = We[k * DD + t];
#pragma unroll
    for (int r = 0; r < ROWS; ++r) {
      acc[r] += sA[r][k] * wn + sE[r][k] * we;
    }
  }
#pragma unroll
  for (int r = 0; r < ROWS; ++r) {
    int row = r0 + r;
    if (row < E) h[(size_t)row * DD + t] = acc[r];
  }
}

// ---------------- degree-normalize + PReLU (in place, float4) ----------------
__global__ __launch_bounds__(256) void prelu_norm(float* __restrict__ buf,
                                                  const float* __restrict__ deg,
                                                  const float* __restrict__ a_ptr,
                                                  int n_rows) {
  int i = blockIdx.x * blockDim.x + threadIdx.x;  // float4 index
  int total = n_rows * (DD / 4);
  if (i >= total) return;
  int row = i >> 5;  // 32 float4 per row
  float dv = deg[row];
  float inv = dv > 0.f ? 1.f / dv : 0.f;
  float a = a_ptr[0];
  float4 v = reinterpret_cast<float4*>(buf)[i];
  v.x *= inv; v.y *= inv; v.z *= inv; v.w *= inv;
  v.x = v.x >= 0.f ? v.x : a * v.x;
  v.y = v.y >= 0.f ? v.y : a * v.y;
  v.z = v.z >= 0.f ? v.z : a * v.z;
  v.w = v.w >= 0.f ? v.w : a * v.w;
  reinterpret_cast<float4*>(buf)[i] = v;
}

extern "C" void kernel_launch(void* const* d_in, const int* in_sizes, int n_in,
                              void* d_out, int out_size, void* d_ws, size_t ws_size,
                              hipStream_t stream) {
  const float* x_in  = (const float*)d_in[0];
  const float* e_in  = (const float*)d_in[1];
  const int*   hidx  = (const int*)d_in[2];
  const float* Wn    = (const float*)d_in[5];
  const float* We    = (const float*)d_in[6];
  const float* bias  = (const float*)d_in[7];
  const float* a_ptr = (const float*)d_in[8];

  const int N   = in_sizes[0] / DD;
  const int E   = in_sizes[1] / DD;
  const int NNZ = in_sizes[2] / 2;
  const int L   = in_sizes[5] / (DD * DD);

  const int* node_idx = hidx;
  const int* edge_idx = hidx + NNZ;

  // workspace layout (512B aligned)
  char* ws = (char*)d_ws;
  size_t off = 0;
  auto take = [&](size_t bytes) {
    void* p = ws + off;
    off = (off + bytes + 511) & ~(size_t)511;
    return p;
  };
  float* deg_v = (float*)take((size_t)N * 4);
  float* deg_e = (float*)take((size_t)E * 4);
  float* agg   = (float*)take((size_t)E * DD * 4);
  float* hbuf  = (float*)take((size_t)E * DD * 4);

  float* xbuf = (float*)d_out;  // node features live in d_out across layers

  // degrees
  hipMemsetAsync(deg_v, 0, (size_t)N * 4, stream);
  hipMemsetAsync(deg_e, 0, (size_t)E * 4, stream);
  deg_kernel<<<(NNZ + 255) / 256, 256, 0, stream>>>(node_idx, edge_idx, deg_v, deg_e, NNZ);

  const float* x_src = x_in;
  for (int l = 0; l < L; ++l) {
    // 1) aggregate node feats onto hyperedges: agg[e] = sum_{v in e} x[v]
    hipMemsetAsync(agg, 0, (size_t)E * DD * 4, stream);
    scatter_rows<<<(NNZ + 7) / 8, 256, 0, stream>>>(x_src, node_idx, edge_idx, agg, NNZ);
    // 2) h = (agg*inv_e)@Wn[l] + e@We[l] + b[l]
    edge_mlp<<<(E + 7) / 8, 128, 0, stream>>>(agg, e_in, deg_e,
                                              Wn + (size_t)l * DD * DD,
                                              We + (size_t)l * DD * DD,
                                              bias + (size_t)l * DD, hbuf, E);
    // 3) scatter hyperedge messages back to nodes
    hipMemsetAsync(xbuf, 0, (size_t)N * DD * 4, stream);
    scatter_rows<<<(NNZ + 7) / 8, 256, 0, stream>>>(hbuf, edge_idx, node_idx, xbuf, NNZ);
    // 4) x = PReLU(sum * inv_v)
    prelu_norm<<<((size_t)N * (DD / 4) + 255) / 256, 256, 0, stream>>>(xbuf, deg_v, a_ptr, N);
    x_src = xbuf;
  }
}

// Round 2
// 1189.486 us; speedup vs baseline: 9.4606x; 9.4606x over previous
//
#include <hip/hip_runtime.h>

#define DD 128  // feature dim

// ======================= CSR build =======================

__global__ __launch_bounds__(256) void hist_kernel(const int* __restrict__ nidx,
                                                   const int* __restrict__ eidx,
                                                   int* __restrict__ cnt_v,
                                                   int* __restrict__ cnt_e, int nnz) {
  int i = blockIdx.x * 256 + threadIdx.x;
  if (i < nnz) {
    atomicAdd(&cnt_v[nidx[i]], 1);
    atomicAdd(&cnt_e[eidx[i]], 1);
  }
}

// each block sums 1024 counts -> partials[blockIdx]
__global__ __launch_bounds__(256) void partial_reduce(const int* __restrict__ cnt, int n,
                                                      int* __restrict__ partials) {
  __shared__ int s[256];
  int t = threadIdx.x;
  int base = blockIdx.x * 1024;
  int sum = 0;
#pragma unroll
  for (int k = 0; k < 4; ++k) {
    int i = base + t * 4 + k;
    if (i < n) sum += cnt[i];
  }
  s[t] = sum;
  __syncthreads();
  for (int o = 128; o > 0; o >>= 1) {
    if (t < o) s[t] += s[t + o];
    __syncthreads();
  }
  if (t == 0) partials[blockIdx.x] = s[0];
}

// single block: exclusive-scan partials (nparts <= 256), write total to rp[n]
__global__ __launch_bounds__(256) void scan_partials(int* __restrict__ partials, int nparts,
                                                     int* __restrict__ rp, int n) {
  __shared__ int s[256];
  int t = threadIdx.x;
  int v = (t < nparts) ? partials[t] : 0;
  s[t] = v;
  __syncthreads();
  for (int o = 1; o < 256; o <<= 1) {
    int add = (t >= o) ? s[t - o] : 0;
    __syncthreads();
    s[t] += add;
    __syncthreads();
  }
  if (t < nparts) partials[t] = s[t] - v;  // exclusive
  if (t == 255) rp[n] = s[255];            // grand total
}

// per-block exclusive scan + block offset; writes rp[i] and cursor copy
__global__ __launch_bounds__(256) void scan_final(const int* __restrict__ cnt,
                                                  const int* __restrict__ partials, int n,
                                                  int* __restrict__ rp, int* __restrict__ cur) {
  __shared__ int s[256];
  int t = threadIdx.x;
  int base = blockIdx.x * 1024;
  int v[4];
  int sum = 0;
#pragma unroll
  for (int k = 0; k < 4; ++k) {
    int i = base + t * 4 + k;
    v[k] = (i < n) ? cnt[i] : 0;
    sum += v[k];
  }
  s[t] = sum;
  __syncthreads();
  int own = sum;
  for (int o = 1; o < 256; o <<= 1) {
    int add = (t >= o) ? s[t - o] : 0;
    __syncthreads();
    s[t] += add;
    __syncthreads();
  }
  int off = partials[blockIdx.x] + (s[t] - own);
#pragma unroll
  for (int k = 0; k < 4; ++k) {
    int i = base + t * 4 + k;
    if (i < n) {
      rp[i] = off;
      cur[i] = off;
      off += v[k];
    }
  }
}

__global__ __launch_bounds__(256) void fill_kernel(const int* __restrict__ nidx,
                                                   const int* __restrict__ eidx,
                                                   int* __restrict__ cur_v,
                                                   int* __restrict__ cur_e,
                                                   int* __restrict__ col_v,
                                                   int* __restrict__ col_e, int nnz) {
  int i = blockIdx.x * 256 + threadIdx.x;
  if (i < nnz) {
    int v = nidx[i], e = eidx[i];
    int p = atomicAdd(&cur_e[e], 1);
    col_e[p] = v;  // node list per hyperedge
    int q = atomicAdd(&cur_v[v], 1);
    col_v[q] = e;  // edge list per node
  }
}

// ======================= pull gathers =======================

// one 64-lane wave per output row; lane owns a float2 slice.
// dst[r] = mean over j in [rp[r],rp[r+1]) of src[col[j]]
__global__ __launch_bounds__(256) void gather_mean(const float* __restrict__ src,
                                                   const int* __restrict__ rp,
                                                   const int* __restrict__ col,
                                                   float* __restrict__ dst, int nrows) {
  int r = blockIdx.x * 4 + (threadIdx.x >> 6);
  if (r >= nrows) return;
  int lane = threadIdx.x & 63;
  int beg = rp[r], end = rp[r + 1];
  float ax = 0.f, ay = 0.f;
  int j = beg;
  for (; j + 4 <= end; j += 4) {
    int s0 = col[j], s1 = col[j + 1], s2 = col[j + 2], s3 = col[j + 3];
    float2 v0 = ((const float2*)(src + (size_t)s0 * DD))[lane];
    float2 v1 = ((const float2*)(src + (size_t)s1 * DD))[lane];
    float2 v2 = ((const float2*)(src + (size_t)s2 * DD))[lane];
    float2 v3 = ((const float2*)(src + (size_t)s3 * DD))[lane];
    ax += v0.x + v1.x + v2.x + v3.x;
    ay += v0.y + v1.y + v2.y + v3.y;
  }
  for (; j < end; ++j) {
    int s = col[j];
    float2 v = ((const float2*)(src + (size_t)s * DD))[lane];
    ax += v.x;
    ay += v.y;
  }
  float inv = (end > beg) ? 1.f / (float)(end - beg) : 0.f;
  float2 o;
  o.x = ax * inv;
  o.y = ay * inv;
  ((float2*)(dst + (size_t)r * DD))[lane] = o;
}

// node-side gather fused with 1/deg_v and PReLU
__global__ __launch_bounds__(256) void gather_prelu(const float* __restrict__ src,
                                                    const int* __restrict__ rp,
                                                    const int* __restrict__ col,
                                                    const float* __restrict__ a_ptr,
                                                    float* __restrict__ dst, int nrows) {
  int r = blockIdx.x * 4 + (threadIdx.x >> 6);
  if (r >= nrows) return;
  int lane = threadIdx.x & 63;
  int beg = rp[r], end = rp[r + 1];
  float ax = 0.f, ay = 0.f;
  int j = beg;
  for (; j + 4 <= end; j += 4) {
    int s0 = col[j], s1 = col[j + 1], s2 = col[j + 2], s3 = col[j + 3];
    float2 v0 = ((const float2*)(src + (size_t)s0 * DD))[lane];
    float2 v1 = ((const float2*)(src + (size_t)s1 * DD))[lane];
    float2 v2 = ((const float2*)(src + (size_t)s2 * DD))[lane];
    float2 v3 = ((const float2*)(src + (size_t)s3 * DD))[lane];
    ax += v0.x + v1.x + v2.x + v3.x;
    ay += v0.y + v1.y + v2.y + v3.y;
  }
  for (; j < end; ++j) {
    int s = col[j];
    float2 v = ((const float2*)(src + (size_t)s * DD))[lane];
    ax += v.x;
    ay += v.y;
  }
  float inv = (end > beg) ? 1.f / (float)(end - beg) : 0.f;
  float a = a_ptr[0];
  ax *= inv;
  ay *= inv;
  ax = ax >= 0.f ? ax : a * ax;
  ay = ay >= 0.f ? ay : a * ay;
  float2 o;
  o.x = ax;
  o.y = ay;
  ((float2*)(dst + (size_t)r * DD))[lane] = o;
}

// ======================= hyperedge MLP =======================
// h[e] = agg[e] @ Wn + ein[e] @ We + b   (agg already mean-scaled)
// In-place safe (h may alias agg): block stages its 8 rows in LDS first.
__global__ __launch_bounds__(128) void edge_mlp(const float* __restrict__ agg,
                                                const float* __restrict__ ein,
                                                const float* __restrict__ Wn,
                                                const float* __restrict__ We,
                                                const float* __restrict__ bias,
                                                float* __restrict__ h, int E) {
  const int ROWS = 8;
  __shared__ float sA[ROWS][DD];
  __shared__ float sE[ROWS][DD];
  int r0 = blockIdx.x * ROWS;
  int t = threadIdx.x;
#pragma unroll
  for (int r = 0; r < ROWS; ++r) {
    int row = r0 + r;
    if (row < E) {
      sA[r][t] = agg[(size_t)row * DD + t];
      sE[r][t] = ein[(size_t)row * DD + t];
    } else {
      sA[r][t] = 0.f;
      sE[r][t] = 0.f;
    }
  }
  __syncthreads();

  float acc[ROWS];
  float bv = bias[t];
#pragma unroll
  for (int r = 0; r < ROWS; ++r) acc[r] = bv;

  for (int k = 0; k < DD; ++k) {
    float wn = Wn[k * DD + t];
    float we = We[k * DD + t];
#pragma unroll
    for (int r = 0; r < ROWS; ++r) {
      acc[r] += sA[r][k] * wn + sE[r][k] * we;
    }
  }
#pragma unroll
  for (int r = 0; r < ROWS; ++r) {
    int row = r0 + r;
    if (row < E) h[(size_t)row * DD + t] = acc[r];
  }
}

// ======================= launch =======================

extern "C" void kernel_launch(void* const* d_in, const int* in_sizes, int n_in,
                              void* d_out, int out_size, void* d_ws, size_t ws_size,
                              hipStream_t stream) {
  const float* x_in  = (const float*)d_in[0];
  const float* e_in  = (const float*)d_in[1];
  const int*   hidx  = (const int*)d_in[2];
  const float* Wn    = (const float*)d_in[5];
  const float* We    = (const float*)d_in[6];
  const float* bias  = (const float*)d_in[7];
  const float* a_ptr = (const float*)d_in[8];

  const int N   = in_sizes[0] / DD;
  const int E   = in_sizes[1] / DD;
  const int NNZ = in_sizes[2] / 2;
  const int L   = in_sizes[5] / (DD * DD);

  const int* node_idx = hidx;
  const int* edge_idx = hidx + NNZ;

  // workspace layout (512B aligned)
  char* ws = (char*)d_ws;
  size_t off = 0;
  auto take = [&](size_t bytes) {
    void* p = ws + off;
    off = (off + bytes + 511) & ~(size_t)511;
    return p;
  };
  int* cnt_v  = (int*)take((size_t)N * 4);
  int* cnt_e  = (int*)take((size_t)E * 4);
  int* rp_v   = (int*)take((size_t)(N + 1) * 4);
  int* rp_e   = (int*)take((size_t)(E + 1) * 4);
  int* cur_v  = (int*)take((size_t)N * 4);
  int* cur_e  = (int*)take((size_t)E * 4);
  int* part_v = (int*)take(256 * 4);
  int* part_e = (int*)take(256 * 4);
  int* col_v  = (int*)take((size_t)NNZ * 4);
  int* col_e  = (int*)take((size_t)NNZ * 4);
  float* agg  = (float*)take((size_t)E * DD * 4);  // reused in-place as h

  float* xbuf = (float*)d_out;  // node features live in d_out across layers

  const int nparts_v = (N + 1023) / 1024;
  const int nparts_e = (E + 1023) / 1024;

  // ---- CSR build (both directions) ----
  hipMemsetAsync(cnt_v, 0, (size_t)N * 4, stream);
  hipMemsetAsync(cnt_e, 0, (size_t)E * 4, stream);
  hist_kernel<<<(NNZ + 255) / 256, 256, 0, stream>>>(node_idx, edge_idx, cnt_v, cnt_e, NNZ);

  partial_reduce<<<nparts_v, 256, 0, stream>>>(cnt_v, N, part_v);
  partial_reduce<<<nparts_e, 256, 0, stream>>>(cnt_e, E, part_e);
  scan_partials<<<1, 256, 0, stream>>>(part_v, nparts_v, rp_v, N);
  scan_partials<<<1, 256, 0, stream>>>(part_e, nparts_e, rp_e, E);
  scan_final<<<nparts_v, 256, 0, stream>>>(cnt_v, part_v, N, rp_v, cur_v);
  scan_final<<<nparts_e, 256, 0, stream>>>(cnt_e, part_e, E, rp_e, cur_e);

  fill_kernel<<<(NNZ + 255) / 256, 256, 0, stream>>>(node_idx, edge_idx, cur_v, cur_e,
                                                     col_v, col_e, NNZ);

  // ---- layers ----
  const float* x_src = x_in;
  for (int l = 0; l < L; ++l) {
    // agg[e] = mean of x[v] over nodes v in hyperedge e
    gather_mean<<<(E + 3) / 4, 256, 0, stream>>>(x_src, rp_e, col_e, agg, E);
    // h = agg@Wn + e@We + b  (in place)
    edge_mlp<<<(E + 7) / 8, 128, 0, stream>>>(agg, e_in,
                                              Wn + (size_t)l * DD * DD,
                                              We + (size_t)l * DD * DD,
                                              bias + (size_t)l * DD, agg, E);
    // x[v] = PReLU( mean over edges e of h[e] )
    gather_prelu<<<(N + 3) / 4, 256, 0, stream>>>(agg, rp_v, col_v, a_ptr, xbuf, N);
    x_src = xbuf;
  }
}

// Round 3
// 1169.524 us; speedup vs baseline: 9.6221x; 1.0171x over previous
//
#include <hip/hip_runtime.h>

#define DD 128  // feature dim

// ======================= CSR build =======================

__global__ __launch_bounds__(256) void hist_kernel(const int* __restrict__ nidx,
                                                   const int* __restrict__ eidx,
                                                   int* __restrict__ cnt_v,
                                                   int* __restrict__ cnt_e, int nnz) {
  int base = (blockIdx.x * 256 + threadIdx.x) * 4;
  if (base + 4 <= nnz) {
    int4 n4 = *reinterpret_cast<const int4*>(nidx + base);
    int4 e4 = *reinterpret_cast<const int4*>(eidx + base);
    atomicAdd(&cnt_v[n4.x], 1);
    atomicAdd(&cnt_v[n4.y], 1);
    atomicAdd(&cnt_v[n4.z], 1);
    atomicAdd(&cnt_v[n4.w], 1);
    atomicAdd(&cnt_e[e4.x], 1);
    atomicAdd(&cnt_e[e4.y], 1);
    atomicAdd(&cnt_e[e4.z], 1);
    atomicAdd(&cnt_e[e4.w], 1);
  } else {
    for (int i = base; i < nnz; ++i) {
      atomicAdd(&cnt_v[nidx[i]], 1);
      atomicAdd(&cnt_e[eidx[i]], 1);
    }
  }
}

// each block sums 1024 counts -> partials[blockIdx]
__global__ __launch_bounds__(256) void partial_reduce(const int* __restrict__ cnt, int n,
                                                      int* __restrict__ partials) {
  __shared__ int s[256];
  int t = threadIdx.x;
  int base = blockIdx.x * 1024;
  int sum = 0;
#pragma unroll
  for (int k = 0; k < 4; ++k) {
    int i = base + t * 4 + k;
    if (i < n) sum += cnt[i];
  }
  s[t] = sum;
  __syncthreads();
  for (int o = 128; o > 0; o >>= 1) {
    if (t < o) s[t] += s[t + o];
    __syncthreads();
  }
  if (t == 0) partials[blockIdx.x] = s[0];
}

// single block: exclusive-scan partials (nparts <= 256), write total to rp[n]
__global__ __launch_bounds__(256) void scan_partials(int* __restrict__ partials, int nparts,
                                                     int* __restrict__ rp, int n) {
  __shared__ int s[256];
  int t = threadIdx.x;
  int v = (t < nparts) ? partials[t] : 0;
  s[t] = v;
  __syncthreads();
  for (int o = 1; o < 256; o <<= 1) {
    int add = (t >= o) ? s[t - o] : 0;
    __syncthreads();
    s[t] += add;
    __syncthreads();
  }
  if (t < nparts) partials[t] = s[t] - v;  // exclusive
  if (t == 255) rp[n] = s[255];            // grand total
}

// per-block exclusive scan + block offset; writes rp[i] and cursor copy
__global__ __launch_bounds__(256) void scan_final(const int* __restrict__ cnt,
                                                  const int* __restrict__ partials, int n,
                                                  int* __restrict__ rp, int* __restrict__ cur) {
  __shared__ int s[256];
  int t = threadIdx.x;
  int base = blockIdx.x * 1024;
  int v[4];
  int sum = 0;
#pragma unroll
  for (int k = 0; k < 4; ++k) {
    int i = base + t * 4 + k;
    v[k] = (i < n) ? cnt[i] : 0;
    sum += v[k];
  }
  s[t] = sum;
  __syncthreads();
  int own = sum;
  for (int o = 1; o < 256; o <<= 1) {
    int add = (t >= o) ? s[t - o] : 0;
    __syncthreads();
    s[t] += add;
    __syncthreads();
  }
  int off = partials[blockIdx.x] + (s[t] - own);
#pragma unroll
  for (int k = 0; k < 4; ++k) {
    int i = base + t * 4 + k;
    if (i < n) {
      rp[i] = off;
      cur[i] = off;
      off += v[k];
    }
  }
}

__global__ __launch_bounds__(256) void fill_kernel(const int* __restrict__ nidx,
                                                   const int* __restrict__ eidx,
                                                   int* __restrict__ cur_v,
                                                   int* __restrict__ cur_e,
                                                   int* __restrict__ col_v,
                                                   int* __restrict__ col_e, int nnz) {
  int base = (blockIdx.x * 256 + threadIdx.x) * 4;
  if (base + 4 <= nnz) {
    int4 n4 = *reinterpret_cast<const int4*>(nidx + base);
    int4 e4 = *reinterpret_cast<const int4*>(eidx + base);
    int p;
    p = atomicAdd(&cur_e[e4.x], 1); col_e[p] = n4.x;
    p = atomicAdd(&cur_e[e4.y], 1); col_e[p] = n4.y;
    p = atomicAdd(&cur_e[e4.z], 1); col_e[p] = n4.z;
    p = atomicAdd(&cur_e[e4.w], 1); col_e[p] = n4.w;
    p = atomicAdd(&cur_v[n4.x], 1); col_v[p] = e4.x;
    p = atomicAdd(&cur_v[n4.y], 1); col_v[p] = e4.y;
    p = atomicAdd(&cur_v[n4.z], 1); col_v[p] = e4.z;
    p = atomicAdd(&cur_v[n4.w], 1); col_v[p] = e4.w;
  } else {
    for (int i = base; i < nnz; ++i) {
      int v = nidx[i], e = eidx[i];
      int p = atomicAdd(&cur_e[e], 1);
      col_e[p] = v;
      int q = atomicAdd(&cur_v[v], 1);
      col_v[q] = e;
    }
  }
}

// ======================= fused edge gather + MLP =======================
// Per block: 16 hyperedge rows.
// Phase 1: 4 waves gather 4 rows each (mean of x[col] rows) + load e rows -> LDS.
// Phase 2: h = sA @ Wn + sE @ We + b, 2 rows x 4 cols per thread, k-vec by 4.
__global__ __launch_bounds__(256) void gather_mlp(const float* __restrict__ x,
                                                  const int* __restrict__ rp,
                                                  const int* __restrict__ col,
                                                  const float* __restrict__ ein,
                                                  const float* __restrict__ Wn,
                                                  const float* __restrict__ We,
                                                  const float* __restrict__ bias,
                                                  float* __restrict__ h, int E) {
  const int ROWS = 16;
  __shared__ float sA[ROWS][DD];
  __shared__ float sE[ROWS][DD];
  int r0 = blockIdx.x * ROWS;
  int wave = threadIdx.x >> 6;
  int lane = threadIdx.x & 63;

  // ---- phase 1: gather ----
#pragma unroll
  for (int rr = 0; rr < 4; ++rr) {
    int li = wave * 4 + rr;
    int row = r0 + li;
    float ax = 0.f, ay = 0.f;
    float2 ev = make_float2(0.f, 0.f);
    if (row < E) {
      int beg = rp[row], end = rp[row + 1];
      int j = beg;
      for (; j + 8 <= end; j += 8) {
        int c[8];
#pragma unroll
        for (int u = 0; u < 8; ++u) c[u] = col[j + u];
#pragma unroll
        for (int u = 0; u < 8; ++u) {
          float2 v = ((const float2*)(x + (size_t)c[u] * DD))[lane];
          ax += v.x;
          ay += v.y;
        }
      }
      for (; j < end; ++j) {
        float2 v = ((const float2*)(x + (size_t)col[j] * DD))[lane];
        ax += v.x;
        ay += v.y;
      }
      float inv = (end > beg) ? 1.f / (float)(end - beg) : 0.f;
      ax *= inv;
      ay *= inv;
      ev = ((const float2*)(ein + (size_t)row * DD))[lane];
    }
    ((float2*)&sA[li][0])[lane] = make_float2(ax, ay);
    ((float2*)&sE[li][0])[lane] = ev;
  }
  __syncthreads();

  // ---- phase 2: MLP ----
  int rg = threadIdx.x >> 5;        // 0..7 -> row pair
  int rA = rg * 2, rB = rA + 1;
  int c0 = (threadIdx.x & 31) * 4;  // 4 consecutive cols
  float acc0[4], acc1[4];
#pragma unroll
  for (int cc = 0; cc < 4; ++cc) {
    float bv = bias[c0 + cc];
    acc0[cc] = bv;
    acc1[cc] = bv;
  }
  for (int k0 = 0; k0 < DD; k0 += 4) {
    float aA[4], aB[4], eA[4], eB[4];
    *(float4*)aA = *(const float4*)&sA[rA][k0];
    *(float4*)aB = *(const float4*)&sA[rB][k0];
    *(float4*)eA = *(const float4*)&sE[rA][k0];
    *(float4*)eB = *(const float4*)&sE[rB][k0];
#pragma unroll
    for (int kk = 0; kk < 4; ++kk) {
      float wn[4], we[4];
      *(float4*)wn = *(const float4*)&Wn[(size_t)(k0 + kk) * DD + c0];
      *(float4*)we = *(const float4*)&We[(size_t)(k0 + kk) * DD + c0];
#pragma unroll
      for (int cc = 0; cc < 4; ++cc) {
        acc0[cc] += aA[kk] * wn[cc] + eA[kk] * we[cc];
        acc1[cc] += aB[kk] * wn[cc] + eB[kk] * we[cc];
      }
    }
  }
  int rowA = r0 + rA, rowB = r0 + rB;
  if (rowA < E)
    *(float4*)&h[(size_t)rowA * DD + c0] = make_float4(acc0[0], acc0[1], acc0[2], acc0[3]);
  if (rowB < E)
    *(float4*)&h[(size_t)rowB * DD + c0] = make_float4(acc1[0], acc1[1], acc1[2], acc1[3]);
}

// ======================= node gather + PReLU =======================
__global__ __launch_bounds__(256) void gather_prelu(const float* __restrict__ src,
                                                    const int* __restrict__ rp,
                                                    const int* __restrict__ col,
                                                    const float* __restrict__ a_ptr,
                                                    float* __restrict__ dst, int nrows) {
  int r = blockIdx.x * 4 + (threadIdx.x >> 6);
  if (r >= nrows) return;
  int lane = threadIdx.x & 63;
  int beg = rp[r], end = rp[r + 1];
  float ax = 0.f, ay = 0.f;
  int j = beg;
  for (; j + 8 <= end; j += 8) {
    int c[8];
#pragma unroll
    for (int u = 0; u < 8; ++u) c[u] = col[j + u];
#pragma unroll
    for (int u = 0; u < 8; ++u) {
      float2 v = ((const float2*)(src + (size_t)c[u] * DD))[lane];
      ax += v.x;
      ay += v.y;
    }
  }
  for (; j < end; ++j) {
    float2 v = ((const float2*)(src + (size_t)col[j] * DD))[lane];
    ax += v.x;
    ay += v.y;
  }
  float inv = (end > beg) ? 1.f / (float)(end - beg) : 0.f;
  float a = a_ptr[0];
  ax *= inv;
  ay *= inv;
  ax = ax >= 0.f ? ax : a * ax;
  ay = ay >= 0.f ? ay : a * ay;
  ((float2*)(dst + (size_t)r * DD))[lane] = make_float2(ax, ay);
}

// ======================= launch =======================

extern "C" void kernel_launch(void* const* d_in, const int* in_sizes, int n_in,
                              void* d_out, int out_size, void* d_ws, size_t ws_size,
                              hipStream_t stream) {
  const float* x_in  = (const float*)d_in[0];
  const float* e_in  = (const float*)d_in[1];
  const int*   hidx  = (const int*)d_in[2];
  const float* Wn    = (const float*)d_in[5];
  const float* We    = (const float*)d_in[6];
  const float* bias  = (const float*)d_in[7];
  const float* a_ptr = (const float*)d_in[8];

  const int N   = in_sizes[0] / DD;
  const int E   = in_sizes[1] / DD;
  const int NNZ = in_sizes[2] / 2;
  const int L   = in_sizes[5] / (DD * DD);

  const int* node_idx = hidx;
  const int* edge_idx = hidx + NNZ;

  // workspace layout (512B aligned)
  char* ws = (char*)d_ws;
  size_t off = 0;
  auto take = [&](size_t bytes) {
    void* p = ws + off;
    off = (off + bytes + 511) & ~(size_t)511;
    return p;
  };
  int* cnt_v  = (int*)take((size_t)N * 4);
  int* cnt_e  = (int*)take((size_t)E * 4);
  int* rp_v   = (int*)take((size_t)(N + 1) * 4);
  int* rp_e   = (int*)take((size_t)(E + 1) * 4);
  int* cur_v  = (int*)take((size_t)N * 4);
  int* cur_e  = (int*)take((size_t)E * 4);
  int* part_v = (int*)take(256 * 4);
  int* part_e = (int*)take(256 * 4);
  int* col_v  = (int*)take((size_t)NNZ * 4);
  int* col_e  = (int*)take((size_t)NNZ * 4);
  float* hbuf = (float*)take((size_t)E * DD * 4);

  float* xbuf = (float*)d_out;  // node features live in d_out across layers

  const int nparts_v = (N + 1023) / 1024;
  const int nparts_e = (E + 1023) / 1024;
  const int nnz4 = (NNZ + 3) / 4;

  // ---- CSR build (both directions) ----
  hipMemsetAsync(cnt_v, 0, (size_t)N * 4, stream);
  hipMemsetAsync(cnt_e, 0, (size_t)E * 4, stream);
  hist_kernel<<<(nnz4 + 255) / 256, 256, 0, stream>>>(node_idx, edge_idx, cnt_v, cnt_e, NNZ);

  partial_reduce<<<nparts_v, 256, 0, stream>>>(cnt_v, N, part_v);
  partial_reduce<<<nparts_e, 256, 0, stream>>>(cnt_e, E, part_e);
  scan_partials<<<1, 256, 0, stream>>>(part_v, nparts_v, rp_v, N);
  scan_partials<<<1, 256, 0, stream>>>(part_e, nparts_e, rp_e, E);
  scan_final<<<nparts_v, 256, 0, stream>>>(cnt_v, part_v, N, rp_v, cur_v);
  scan_final<<<nparts_e, 256, 0, stream>>>(cnt_e, part_e, E, rp_e, cur_e);

  fill_kernel<<<(nnz4 + 255) / 256, 256, 0, stream>>>(node_idx, edge_idx, cur_v, cur_e,
                                                      col_v, col_e, NNZ);

  // ---- layers ----
  const float* x_src = x_in;
  for (int l = 0; l < L; ++l) {
    gather_mlp<<<(E + 15) / 16, 256, 0, stream>>>(x_src, rp_e, col_e, e_in,
                                                  Wn + (size_t)l * DD * DD,
                                                  We + (size_t)l * DD * DD,
                                                  bias + (size_t)l * DD, hbuf, E);
    gather_prelu<<<(N + 3) / 4, 256, 0, stream>>>(hbuf, rp_v, col_v, a_ptr, xbuf, N);
    x_src = xbuf;
  }
}

// Round 4
// 1166.351 us; speedup vs baseline: 9.6482x; 1.0027x over previous
//
#include <hip/hip_runtime.h>

#define DD 128  // feature dim
#define FILL_BUCKETS 16
#define FILL_CHUNK 16384  // COO entries per block

// ======================= CSR build =======================

__global__ __launch_bounds__(256) void hist_kernel(const int* __restrict__ nidx,
                                                   const int* __restrict__ eidx,
                                                   int* __restrict__ cnt_v,
                                                   int* __restrict__ cnt_e, int nnz) {
  int base = (blockIdx.x * 256 + threadIdx.x) * 4;
  if (base + 4 <= nnz) {
    int4 n4 = *reinterpret_cast<const int4*>(nidx + base);
    int4 e4 = *reinterpret_cast<const int4*>(eidx + base);
    atomicAdd(&cnt_v[n4.x], 1);
    atomicAdd(&cnt_v[n4.y], 1);
    atomicAdd(&cnt_v[n4.z], 1);
    atomicAdd(&cnt_v[n4.w], 1);
    atomicAdd(&cnt_e[e4.x], 1);
    atomicAdd(&cnt_e[e4.y], 1);
    atomicAdd(&cnt_e[e4.z], 1);
    atomicAdd(&cnt_e[e4.w], 1);
  } else {
    for (int i = base; i < nnz; ++i) {
      atomicAdd(&cnt_v[nidx[i]], 1);
      atomicAdd(&cnt_e[eidx[i]], 1);
    }
  }
}

// each block sums 1024 counts -> partials[blockIdx]
__global__ __launch_bounds__(256) void partial_reduce(const int* __restrict__ cnt, int n,
                                                      int* __restrict__ partials) {
  __shared__ int s[256];
  int t = threadIdx.x;
  int base = blockIdx.x * 1024;
  int sum = 0;
#pragma unroll
  for (int k = 0; k < 4; ++k) {
    int i = base + t * 4 + k;
    if (i < n) sum += cnt[i];
  }
  s[t] = sum;
  __syncthreads();
  for (int o = 128; o > 0; o >>= 1) {
    if (t < o) s[t] += s[t + o];
    __syncthreads();
  }
  if (t == 0) partials[blockIdx.x] = s[0];
}

// single block: exclusive-scan partials (nparts <= 256), write total to rp[n]
__global__ __launch_bounds__(256) void scan_partials(int* __restrict__ partials, int nparts,
                                                     int* __restrict__ rp, int n) {
  __shared__ int s[256];
  int t = threadIdx.x;
  int v = (t < nparts) ? partials[t] : 0;
  s[t] = v;
  __syncthreads();
  for (int o = 1; o < 256; o <<= 1) {
    int add = (t >= o) ? s[t - o] : 0;
    __syncthreads();
    s[t] += add;
    __syncthreads();
  }
  if (t < nparts) partials[t] = s[t] - v;  // exclusive
  if (t == 255) rp[n] = s[255];            // grand total
}

// per-block exclusive scan + block offset; writes rp[i] and cursor copy
__global__ __launch_bounds__(256) void scan_final(const int* __restrict__ cnt,
                                                  const int* __restrict__ partials, int n,
                                                  int* __restrict__ rp, int* __restrict__ cur) {
  __shared__ int s[256];
  int t = threadIdx.x;
  int base = blockIdx.x * 1024;
  int v[4];
  int sum = 0;
#pragma unroll
  for (int k = 0; k < 4; ++k) {
    int i = base + t * 4 + k;
    v[k] = (i < n) ? cnt[i] : 0;
    sum += v[k];
  }
  s[t] = sum;
  __syncthreads();
  int own = sum;
  for (int o = 1; o < 256; o <<= 1) {
    int add = (t >= o) ? s[t - o] : 0;
    __syncthreads();
    s[t] += add;
    __syncthreads();
  }
  int off = partials[blockIdx.x] + (s[t] - own);
#pragma unroll
  for (int k = 0; k < 4; ++k) {
    int i = base + t * 4 + k;
    if (i < n) {
      rp[i] = off;
      cur[i] = off;
      off += v[k];
    }
  }
}

// Bucketed counting-sort fill: block (bucket, chunk) scans its COO chunk and
// commits only keys in [bucket*bsize, (bucket+1)*bsize). bucket = blockIdx%16
// -> bucket always on the same XCD (16 % 8 == 0), so each bucket's output
// window + cursors stay resident in ONE XCD's L2 -> full-line writebacks.
__global__ __launch_bounds__(256) void fill_bucketed(const int* __restrict__ key,
                                                     const int* __restrict__ val,
                                                     int* __restrict__ cur,
                                                     int* __restrict__ colout,
                                                     int nnz, int bsize) {
  int bucket = blockIdx.x & (FILL_BUCKETS - 1);
  int chunk = blockIdx.x / FILL_BUCKETS;
  int lo = bucket * bsize;
  int hi = lo + bsize;
  int cbeg = chunk * FILL_CHUNK;
  int cend = min(nnz, cbeg + FILL_CHUNK);
  for (int i = cbeg + threadIdx.x * 4; i < cend; i += 256 * 4) {
    if (i + 4 <= cend) {
      int4 k4 = *reinterpret_cast<const int4*>(key + i);
      int4 v4 = *reinterpret_cast<const int4*>(val + i);
      if (k4.x >= lo && k4.x < hi) { int p = atomicAdd(&cur[k4.x], 1); colout[p] = v4.x; }
      if (k4.y >= lo && k4.y < hi) { int p = atomicAdd(&cur[k4.y], 1); colout[p] = v4.y; }
      if (k4.z >= lo && k4.z < hi) { int p = atomicAdd(&cur[k4.z], 1); colout[p] = v4.z; }
      if (k4.w >= lo && k4.w < hi) { int p = atomicAdd(&cur[k4.w], 1); colout[p] = v4.w; }
    } else {
      for (int j = i; j < cend; ++j) {
        int k = key[j];
        if (k >= lo && k < hi) { int p = atomicAdd(&cur[k], 1); colout[p] = val[j]; }
      }
    }
  }
}

// ======================= fused edge gather + MLP =======================
// 512 threads, 16 rows/block. Phase 1: 8 waves x 2 rows, 16-deep gather ILP.
// Phase 2: h = sA @ Wn + sE @ We + b; thread = 1 row x 4 cols.
__global__ __launch_bounds__(512) void gather_mlp(const float* __restrict__ x,
                                                  const int* __restrict__ rp,
                                                  const int* __restrict__ col,
                                                  const float* __restrict__ ein,
                                                  const float* __restrict__ Wn,
                                                  const float* __restrict__ We,
                                                  const float* __restrict__ bias,
                                                  float* __restrict__ h, int E) {
  const int ROWS = 16;
  __shared__ float sA[ROWS][DD];
  __shared__ float sE[ROWS][DD];
  int r0 = blockIdx.x * ROWS;
  int wave = threadIdx.x >> 6;
  int lane = threadIdx.x & 63;

  // ---- phase 1: gather (2 rows per wave, 16-deep) ----
#pragma unroll
  for (int rr = 0; rr < 2; ++rr) {
    int li = wave * 2 + rr;
    int row = r0 + li;
    float ax = 0.f, ay = 0.f;
    float2 ev = make_float2(0.f, 0.f);
    if (row < E) {
      int beg = rp[row], end = rp[row + 1];
      int j = beg;
      for (; j + 16 <= end; j += 16) {
        int c[16];
#pragma unroll
        for (int u = 0; u < 16; ++u) c[u] = col[j + u];
        float2 v[16];
#pragma unroll
        for (int u = 0; u < 16; ++u) v[u] = ((const float2*)(x + (size_t)c[u] * DD))[lane];
#pragma unroll
        for (int u = 0; u < 16; ++u) {
          ax += v[u].x;
          ay += v[u].y;
        }
      }
      for (; j + 4 <= end; j += 4) {
        int c[4];
#pragma unroll
        for (int u = 0; u < 4; ++u) c[u] = col[j + u];
#pragma unroll
        for (int u = 0; u < 4; ++u) {
          float2 v = ((const float2*)(x + (size_t)c[u] * DD))[lane];
          ax += v.x;
          ay += v.y;
        }
      }
      for (; j < end; ++j) {
        float2 v = ((const float2*)(x + (size_t)col[j] * DD))[lane];
        ax += v.x;
        ay += v.y;
      }
      float inv = (end > beg) ? 1.f / (float)(end - beg) : 0.f;
      ax *= inv;
      ay *= inv;
      ev = ((const float2*)(ein + (size_t)row * DD))[lane];
    }
    ((float2*)&sA[li][0])[lane] = make_float2(ax, ay);
    ((float2*)&sE[li][0])[lane] = ev;
  }
  __syncthreads();

  // ---- phase 2: MLP ----
  int rg = threadIdx.x >> 5;        // 0..15 -> row
  int c0 = (threadIdx.x & 31) * 4;  // 4 consecutive cols
  float acc[4];
  float bv[4];
  *(float4*)bv = *(const float4*)&bias[c0];
#pragma unroll
  for (int cc = 0; cc < 4; ++cc) acc[cc] = bv[cc];

  for (int k0 = 0; k0 < DD; k0 += 4) {
    float aA[4], eA[4];
    *(float4*)aA = *(const float4*)&sA[rg][k0];
    *(float4*)eA = *(const float4*)&sE[rg][k0];
#pragma unroll
    for (int kk = 0; kk < 4; ++kk) {
      float wn[4], we[4];
      *(float4*)wn = *(const float4*)&Wn[(size_t)(k0 + kk) * DD + c0];
      *(float4*)we = *(const float4*)&We[(size_t)(k0 + kk) * DD + c0];
#pragma unroll
      for (int cc = 0; cc < 4; ++cc) {
        acc[cc] += aA[kk] * wn[cc] + eA[kk] * we[cc];
      }
    }
  }
  int row = r0 + rg;
  if (row < E)
    *(float4*)&h[(size_t)row * DD + c0] = make_float4(acc[0], acc[1], acc[2], acc[3]);
}

// ======================= node gather + PReLU =======================
__global__ __launch_bounds__(256) void gather_prelu(const float* __restrict__ src,
                                                    const int* __restrict__ rp,
                                                    const int* __restrict__ col,
                                                    const float* __restrict__ a_ptr,
                                                    float* __restrict__ dst, int nrows) {
  int r = blockIdx.x * 4 + (threadIdx.x >> 6);
  if (r >= nrows) return;
  int lane = threadIdx.x & 63;
  int beg = rp[r], end = rp[r + 1];
  float ax = 0.f, ay = 0.f;
  int j = beg;
  for (; j + 16 <= end; j += 16) {
    int c[16];
#pragma unroll
    for (int u = 0; u < 16; ++u) c[u] = col[j + u];
    float2 v[16];
#pragma unroll
    for (int u = 0; u < 16; ++u) v[u] = ((const float2*)(src + (size_t)c[u] * DD))[lane];
#pragma unroll
    for (int u = 0; u < 16; ++u) {
      ax += v[u].x;
      ay += v[u].y;
    }
  }
  for (; j + 4 <= end; j += 4) {
    int c[4];
#pragma unroll
    for (int u = 0; u < 4; ++u) c[u] = col[j + u];
#pragma unroll
    for (int u = 0; u < 4; ++u) {
      float2 v = ((const float2*)(src + (size_t)c[u] * DD))[lane];
      ax += v.x;
      ay += v.y;
    }
  }
  for (; j < end; ++j) {
    float2 v = ((const float2*)(src + (size_t)col[j] * DD))[lane];
    ax += v.x;
    ay += v.y;
  }
  float inv = (end > beg) ? 1.f / (float)(end - beg) : 0.f;
  float a = a_ptr[0];
  ax *= inv;
  ay *= inv;
  ax = ax >= 0.f ? ax : a * ax;
  ay = ay >= 0.f ? ay : a * ay;
  ((float2*)(dst + (size_t)r * DD))[lane] = make_float2(ax, ay);
}

// ======================= launch =======================

extern "C" void kernel_launch(void* const* d_in, const int* in_sizes, int n_in,
                              void* d_out, int out_size, void* d_ws, size_t ws_size,
                              hipStream_t stream) {
  const float* x_in  = (const float*)d_in[0];
  const float* e_in  = (const float*)d_in[1];
  const int*   hidx  = (const int*)d_in[2];
  const float* Wn    = (const float*)d_in[5];
  const float* We    = (const float*)d_in[6];
  const float* bias  = (const float*)d_in[7];
  const float* a_ptr = (const float*)d_in[8];

  const int N   = in_sizes[0] / DD;
  const int E   = in_sizes[1] / DD;
  const int NNZ = in_sizes[2] / 2;
  const int L   = in_sizes[5] / (DD * DD);

  const int* node_idx = hidx;
  const int* edge_idx = hidx + NNZ;

  // workspace layout (512B aligned)
  char* ws = (char*)d_ws;
  size_t off = 0;
  auto take = [&](size_t bytes) {
    void* p = ws + off;
    off = (off + bytes + 511) & ~(size_t)511;
    return p;
  };
  int* cnt_v  = (int*)take((size_t)N * 4);
  int* cnt_e  = (int*)take((size_t)E * 4);
  int* rp_v   = (int*)take((size_t)(N + 1) * 4);
  int* rp_e   = (int*)take((size_t)(E + 1) * 4);
  int* cur_v  = (int*)take((size_t)N * 4);
  int* cur_e  = (int*)take((size_t)E * 4);
  int* part_v = (int*)take(256 * 4);
  int* part_e = (int*)take(256 * 4);
  int* col_v  = (int*)take((size_t)NNZ * 4);
  int* col_e  = (int*)take((size_t)NNZ * 4);
  float* hbuf = (float*)take((size_t)E * DD * 4);

  float* xbuf = (float*)d_out;  // node features live in d_out across layers

  const int nparts_v = (N + 1023) / 1024;
  const int nparts_e = (E + 1023) / 1024;
  const int nnz4 = (NNZ + 3) / 4;
  const int nchunks = (NNZ + FILL_CHUNK - 1) / FILL_CHUNK;
  const int bsize_e = (E + FILL_BUCKETS - 1) / FILL_BUCKETS;
  const int bsize_v = (N + FILL_BUCKETS - 1) / FILL_BUCKETS;

  // ---- CSR build (both directions) ----
  hipMemsetAsync(cnt_v, 0, (size_t)N * 4, stream);
  hipMemsetAsync(cnt_e, 0, (size_t)E * 4, stream);
  hist_kernel<<<(nnz4 + 255) / 256, 256, 0, stream>>>(node_idx, edge_idx, cnt_v, cnt_e, NNZ);

  partial_reduce<<<nparts_v, 256, 0, stream>>>(cnt_v, N, part_v);
  partial_reduce<<<nparts_e, 256, 0, stream>>>(cnt_e, E, part_e);
  scan_partials<<<1, 256, 0, stream>>>(part_v, nparts_v, rp_v, N);
  scan_partials<<<1, 256, 0, stream>>>(part_e, nparts_e, rp_e, E);
  scan_final<<<nparts_v, 256, 0, stream>>>(cnt_v, part_v, N, rp_v, cur_v);
  scan_final<<<nparts_e, 256, 0, stream>>>(cnt_e, part_e, E, rp_e, cur_e);

  // bucketed fills: key=edge -> col_e gets node list; key=node -> col_v gets edge list
  fill_bucketed<<<nchunks * FILL_BUCKETS, 256, 0, stream>>>(edge_idx, node_idx, cur_e,
                                                            col_e, NNZ, bsize_e);
  fill_bucketed<<<nchunks * FILL_BUCKETS, 256, 0, stream>>>(node_idx, edge_idx, cur_v,
                                                            col_v, NNZ, bsize_v);

  // ---- layers ----
  const float* x_src = x_in;
  for (int l = 0; l < L; ++l) {
    gather_mlp<<<(E + 15) / 16, 512, 0, stream>>>(x_src, rp_e, col_e, e_in,
                                                  Wn + (size_t)l * DD * DD,
                                                  We + (size_t)l * DD * DD,
                                                  bias + (size_t)l * DD, hbuf, E);
    gather_prelu<<<(N + 3) / 4, 256, 0, stream>>>(hbuf, rp_v, col_v, a_ptr, xbuf, N);
    x_src = xbuf;
  }
}